// Round 10
// baseline (369.655 us; speedup 1.0000x reference)
//
#include <hip/hip_runtime.h>
#include <hip/hip_bf16.h>

#define GAT_N 8192
#define GAT_K 256
#define GAT_D 64
#define GAT_ALPHA 0.2f
#define GAT_FILL 1e-15f

typedef float f32x4 __attribute__((ext_vector_type(4)));
typedef short bf16x8 __attribute__((ext_vector_type(8)));

static __device__ __forceinline__ unsigned f2bf_u(float x) {
  unsigned u = __float_as_uint(x);
  u += 0x7FFFu + ((u >> 16) & 1u);
  return u >> 16;
}

static __device__ __forceinline__ float rfl(float x) {
  return __uint_as_float(__builtin_amdgcn_readfirstlane(__float_as_uint(x)));
}

// ---------------------------------------------------------------------------
// Kernel 1: register-tiled Wh = h @ W (validated round 4, unchanged).
// ---------------------------------------------------------------------------
__global__ __launch_bounds__(256) void k_prep(const float* __restrict__ h,
                                              const float* __restrict__ W,
                                              const float* __restrict__ av,
                                              float* __restrict__ s_src,
                                              float* __restrict__ s_dst,
                                              short* __restrict__ WhT,
                                              float* __restrict__ bmax) {
  __shared__ short T[4][64][8];
  __shared__ float wmLds[4];
  const int tid = threadIdx.x;
  const int wv = tid >> 6, lane = tid & 63;
  const int r0 = blockIdx.x * 32 + wv * 8;

  float acc[8], acc2[8];
#pragma unroll
  for (int r = 0; r < 8; ++r) { acc[r] = 0.f; acc2[r] = 0.f; }

  for (int kc = 0; kc < GAT_K; kc += 32) {
    float Wreg[32];
#pragma unroll
    for (int e = 0; e < 32; ++e) Wreg[e] = W[(size_t)(kc + e) * GAT_D + lane];
#pragma unroll
    for (int r = 0; r < 8; ++r) {
      const f32x4* h4 = (const f32x4*)(h + (size_t)(r0 + r) * GAT_K + kc);
#pragma unroll
      for (int q = 0; q < 8; ++q) {
        f32x4 hv = h4[q];
        acc[r] += hv[0] * Wreg[4 * q + 0];
        acc2[r] += hv[1] * Wreg[4 * q + 1];
        acc[r] += hv[2] * Wreg[4 * q + 2];
        acc2[r] += hv[3] * Wreg[4 * q + 3];
      }
    }
  }

  const float a_s = av[lane];
  const float a_d = av[64 + lane];
  float wmax = -3.0e38f;
#pragma unroll
  for (int r = 0; r < 8; ++r) {
    const float accf = acc[r] + acc2[r];
    T[wv][lane][r] = (short)f2bf_u(accf);
    float vs = accf * a_s, vd = accf * a_d;
#pragma unroll
    for (int off = 32; off > 0; off >>= 1) {
      vs += __shfl_xor(vs, off);
      vd += __shfl_xor(vd, off);
    }
    if (lane == 0) { s_src[r0 + r] = vs; s_dst[r0 + r] = vd; }
    wmax = fmaxf(wmax, vd);
  }
  bf16x8 vt = *(const bf16x8*)&T[wv][lane][0];
  *(bf16x8*)(WhT + (size_t)lane * GAT_N + r0) = vt;

  if (lane == 0) wmLds[wv] = wmax;
  __syncthreads();
  if (tid == 0) {
    bmax[blockIdx.x] = fmaxf(fmaxf(wmLds[0], wmLds[1]), fmaxf(wmLds[2], wmLds[3]));
  }
}

// ---------------------------------------------------------------------------
// Kernel 2: round-9 kernel with an internal nrep repeat (DIAGNOSTIC):
// each rep re-reads the (unchanged) inputs, re-inits acc, recomputes, and
// rewrites the same output -> bit-identical result, deterministic. nrep=3
// makes this dispatch ~300us so it surfaces ABOVE the harness poison fills
// in the rocprof top-5, exposing its true counters (VALUBusy/MfmaUtil/
// FETCH_SIZE/LDS conflicts/Occupancy) for the first time.
// ---------------------------------------------------------------------------
#define BM 16
#define JB 1024
#define NCHUNK (GAT_N / JB)
#define NWAVE 8

__global__ __launch_bounds__(512, 4) void k_attn(
    const float* __restrict__ A,
    const float* __restrict__ s_src,
    const float* __restrict__ s_dst,
    const short* __restrict__ WhT,
    const float* __restrict__ bmax,
    float* __restrict__ out,
    int nrep) {
  __shared__ char smem[65536];  // 2 x [16][1024] bf16 swizzled tiles; epilogue reuse

  const int tid = threadIdx.x;
  const int wv = tid >> 6, lane = tid & 63;
  const int rsub = lane & 15, kg = lane >> 4;
  const int i0 = blockIdx.x * BM;
  const int par = wv >> 2;          // wave-uniform: 0 for tid<256, 1 for tid>=256
  const int cth = tid & 255;        // column-thread index within parity group

  // global max of s_dst from 256 per-block maxima
  float bm = fmaxf(fmaxf(bmax[lane], bmax[lane + 64]),
                   fmaxf(bmax[lane + 128], bmax[lane + 192]));
#pragma unroll
  for (int off = 32; off > 0; off >>= 1) bm = fmaxf(bm, __shfl_xor(bm, off));
  const float tmax = bm;

  // per-row wave-uniform constants (rows r = 2*s + par)
  float F1_[8], F2_[8], ns_[8], c_[8];
#pragma unroll
  for (int s = 0; s < 8; ++s) {
    float sc = s_src[i0 + 2 * s + par];
    float x0 = sc + tmax;
    float m = fmaxf(fmaxf(x0, GAT_ALPHA * x0), GAT_FILL);
    F1_[s] = rfl(__expf(sc - m));
    F2_[s] = rfl(__expf(GAT_ALPHA * sc - m));
    ns_[s] = rfl(-sc);
    c_[s] = rfl(__expf(GAT_FILL - m));
  }

  bf16x8 ones;
#pragma unroll
  for (int e = 0; e < 8; ++e) ones[e] = (short)0x3F80;

  const short* pb0 = WhT + (size_t)(0 * 16 + rsub) * GAT_N;
  const short* pb1 = WhT + (size_t)(1 * 16 + rsub) * GAT_N;
  const short* pb2 = WhT + (size_t)(2 * 16 + rsub) * GAT_N;
  const short* pb3 = WhT + (size_t)(3 * 16 + rsub) * GAT_N;

  const float* Abase = A + (size_t)(i0 + par) * GAT_N + cth * 4;
  auto aaddr = [&](int g) {
    return Abase + (size_t)((g & 7) * 2) * GAT_N + (size_t)(g >> 3) * JB;
  };

  for (int rep = 0; rep < nrep; ++rep) {
    f32x4 acc0 = {0.f, 0.f, 0.f, 0.f};
    f32x4 acc1 = {0.f, 0.f, 0.f, 0.f};
    f32x4 acc2 = {0.f, 0.f, 0.f, 0.f};
    f32x4 acc3 = {0.f, 0.f, 0.f, 0.f};
    f32x4 accl = {0.f, 0.f, 0.f, 0.f};

    f32x4 buf[4];
#pragma unroll
    for (int g = 0; g < 4; ++g) buf[g] = *(const f32x4*)aaddr(g);

    for (int chunk = 0; chunk < NCHUNK; ++chunk) {
      const int jc = chunk * JB;
      const int tile = (chunk & 1) << 15;  // 0 or 32768
      const f32x4 t = *(const f32x4*)(s_dst + jc + cth * 4);

      // per-chunk exps, shared across all 16 rows
      f32x4 E1, E2;
#pragma unroll
      for (int e = 0; e < 4; ++e) {
        E1[e] = __expf(t[e]);
        E2[e] = __expf(GAT_ALPHA * t[e]);
      }

      // ---- stage phase: 8 steps, 4-deep load pipeline ----
#pragma unroll
      for (int s = 0; s < 8; ++s) {
        const int g = chunk * 8 + s;
        f32x4 av = buf[g & 3];
        if (g + 4 < 64) buf[(g + 4) & 3] = *(const f32x4*)aaddr(g + 4);
        const float F1 = F1_[s], F2 = F2_[s], negs = ns_[s], cc = c_[s];
        float p[4];
#pragma unroll
        for (int e = 0; e < 4; ++e) {
          float m1 = E1[e] * F1;
          float m2 = E2[e] * F2;
          float psel = (t[e] >= negs) ? m1 : m2;
          p[e] = (av[e] > 0.f) ? psel : cc;
        }
        __hip_bfloat162 pa = __float22bfloat162_rn(float2{p[0], p[1]});
        __hip_bfloat162 pb = __float22bfloat162_rn(float2{p[2], p[3]});
        uint2 w;
        __builtin_memcpy(&w.x, &pa, 4);
        __builtin_memcpy(&w.y, &pb, 4);
        const int row = 2 * s + par;
        *(uint2*)(&smem[tile + (row << 11) + (((cth << 3)) ^ ((row & 7) << 4))]) = w;
      }
      __syncthreads();  // tile ready; also orders MFMA(c-1) before stage(c+1)

      // ---- MFMA phase: wave wv consumes cols [jc + wv*128, +128) ----
#pragma unroll
      for (int kq = 0; kq < 4; ++kq) {
        const int cbyte = (wv << 8) + (kq << 6) + (kg << 4);
        bf16x8 af = *(const bf16x8*)(&smem[tile + (rsub << 11) + (cbyte ^ ((rsub & 7) << 4))]);
        const int bcol = jc + (wv << 7) + (kq << 5) + (kg << 3);
        bf16x8 b0 = *(const bf16x8*)(pb0 + bcol);
        bf16x8 b1 = *(const bf16x8*)(pb1 + bcol);
        bf16x8 b2 = *(const bf16x8*)(pb2 + bcol);
        bf16x8 b3 = *(const bf16x8*)(pb3 + bcol);
        acc0 = __builtin_amdgcn_mfma_f32_16x16x32_bf16(af, b0, acc0, 0, 0, 0);
        acc1 = __builtin_amdgcn_mfma_f32_16x16x32_bf16(af, b1, acc1, 0, 0, 0);
        acc2 = __builtin_amdgcn_mfma_f32_16x16x32_bf16(af, b2, acc2, 0, 0, 0);
        acc3 = __builtin_amdgcn_mfma_f32_16x16x32_bf16(af, b3, acc3, 0, 0, 0);
        accl = __builtin_amdgcn_mfma_f32_16x16x32_bf16(af, ones, accl, 0, 0, 0);
      }
      // no trailing barrier: next stage writes the OTHER tile.
    }

    __syncthreads();  // all MFMA done before smem reuse

    // ---- epilogue: exact cross-wave combine + ELU (smem reused) ----
    float* lds_o = (float*)smem;            // [8][16][64] f32 = 32 KB
    float* lds_l = (float*)(smem + 32768);  // [8][16]
#pragma unroll
    for (int r = 0; r < 4; ++r) {
      const int orow = kg * 4 + r;  // C/D layout: col = lane&15, row = kg*4+reg
      lds_o[wv * 1024 + orow * 64 + 0 * 16 + rsub] = acc0[r];
      lds_o[wv * 1024 + orow * 64 + 1 * 16 + rsub] = acc1[r];
      lds_o[wv * 1024 + orow * 64 + 2 * 16 + rsub] = acc2[r];
      lds_o[wv * 1024 + orow * 64 + 3 * 16 + rsub] = acc3[r];
      if (rsub == 0) lds_l[wv * 16 + orow] = accl[r];
    }
    __syncthreads();

    for (int idx = tid; idx < BM * GAT_D; idx += 512) {
      const int r = idx >> 6, c = idx & 63;
      float o = 0.f, ll = 0.f;
#pragma unroll
      for (int w = 0; w < NWAVE; ++w) {
        o += lds_o[w * 1024 + r * 64 + c];
        ll += lds_l[w * 16 + r];
      }
      float val = o / ll;
      out[(size_t)(i0 + r) * GAT_D + c] = (val > 0.f) ? val : (__expf(val) - 1.f);
    }
    __syncthreads();  // epilogue reads done before next rep's stage writes
  }
}

// ---------------------------------------------------------------------------
extern "C" void kernel_launch(void* const* d_in, const int* in_sizes, int n_in,
                              void* d_out, int out_size, void* d_ws, size_t ws_size,
                              hipStream_t stream) {
  const float* h = (const float*)d_in[0];
  const float* A = (const float*)d_in[1];
  const float* W = (const float*)d_in[2];
  const float* a = (const float*)d_in[3];
  float* out = (float*)d_out;

  // ws layout: [0,1K) bmax | [4K,+32K) s_src | [36864,+32K) s_dst | [69632,+1M) WhT
  const size_t need = 69632 + (size_t)GAT_D * GAT_N * 2;
  if (ws_size < need) return;
  float* bmax = (float*)d_ws;
  float* s_src = (float*)((char*)d_ws + 4096);
  float* s_dst = (float*)((char*)d_ws + 36864);
  short* WhT = (short*)((char*)d_ws + 69632);

  k_prep<<<dim3(256), dim3(256), 0, stream>>>(h, W, a, s_src, s_dst, WhT, bmax);
  // DIAGNOSTIC: nrep=3 -> ~300us dispatch, surfaces above the poison fills
  // in the rocprof top-5 so we finally see this kernel's counters.
  k_attn<<<dim3(GAT_N / BM), dim3(512), 0, stream>>>(A, s_src, s_dst, WhT, bmax,
                                                     out, 3);
}

// Round 11
// 158.975 us; speedup vs baseline: 2.3252x; 2.3252x over previous
//
#include <hip/hip_runtime.h>
#include <hip/hip_bf16.h>

#define GAT_N 8192
#define GAT_K 256
#define GAT_D 64
#define GAT_ALPHA 0.2f
#define GAT_FILL 1e-15f

typedef float f32x4 __attribute__((ext_vector_type(4)));
typedef short bf16x8 __attribute__((ext_vector_type(8)));

static __device__ __forceinline__ unsigned f2bf_u(float x) {
  unsigned u = __float_as_uint(x);
  u += 0x7FFFu + ((u >> 16) & 1u);
  return u >> 16;
}

// ---------------------------------------------------------------------------
// Kernel 1: register-tiled Wh = h @ W (validated round 4, unchanged).
// ---------------------------------------------------------------------------
__global__ __launch_bounds__(256) void k_prep(const float* __restrict__ h,
                                              const float* __restrict__ W,
                                              const float* __restrict__ av,
                                              float* __restrict__ s_src,
                                              float* __restrict__ s_dst,
                                              short* __restrict__ WhT,
                                              float* __restrict__ bmax) {
  __shared__ short T[4][64][8];
  __shared__ float wmLds[4];
  const int tid = threadIdx.x;
  const int wv = tid >> 6, lane = tid & 63;
  const int r0 = blockIdx.x * 32 + wv * 8;

  float acc[8], acc2[8];
#pragma unroll
  for (int r = 0; r < 8; ++r) { acc[r] = 0.f; acc2[r] = 0.f; }

  for (int kc = 0; kc < GAT_K; kc += 32) {
    float Wreg[32];
#pragma unroll
    for (int e = 0; e < 32; ++e) Wreg[e] = W[(size_t)(kc + e) * GAT_D + lane];
#pragma unroll
    for (int r = 0; r < 8; ++r) {
      const f32x4* h4 = (const f32x4*)(h + (size_t)(r0 + r) * GAT_K + kc);
#pragma unroll
      for (int q = 0; q < 8; ++q) {
        f32x4 hv = h4[q];
        acc[r] += hv[0] * Wreg[4 * q + 0];
        acc2[r] += hv[1] * Wreg[4 * q + 1];
        acc[r] += hv[2] * Wreg[4 * q + 2];
        acc2[r] += hv[3] * Wreg[4 * q + 3];
      }
    }
  }

  const float a_s = av[lane];
  const float a_d = av[64 + lane];
  float wmax = -3.0e38f;
#pragma unroll
  for (int r = 0; r < 8; ++r) {
    const float accf = acc[r] + acc2[r];
    T[wv][lane][r] = (short)f2bf_u(accf);
    float vs = accf * a_s, vd = accf * a_d;
#pragma unroll
    for (int off = 32; off > 0; off >>= 1) {
      vs += __shfl_xor(vs, off);
      vd += __shfl_xor(vd, off);
    }
    if (lane == 0) { s_src[r0 + r] = vs; s_dst[r0 + r] = vd; }
    wmax = fmaxf(wmax, vd);
  }
  bf16x8 vt = *(const bf16x8*)&T[wv][lane][0];
  *(bf16x8*)(WhT + (size_t)lane * GAT_N + r0) = vt;

  if (lane == 0) wmLds[wv] = wmax;
  __syncthreads();
  if (tid == 0) {
    bmax[blockIdx.x] = fmaxf(fmaxf(wmLds[0], wmLds[1]), fmaxf(wmLds[2], wmLds[3]));
  }
}

// ---------------------------------------------------------------------------
// Kernel 2: BARRIER-FREE main loop + full occupancy.
//   grid = 1024 blocks (16-row tile x 2 j-halves of 4096 cols), 512 thr.
//   Each wave owns a PRIVATE 4 KB P tile ([16][128] bf16, XOR-swizzled) and
//   processes 4 chunks of 128 cols: stage (8 steps: A f32x4 load -> lrelu/
//   mask/exp -> cvt_pk -> ds_write_b64) then 4x(ds_read_b128 + 4 B-loads +
//   5 MFMAs). No __syncthreads in the loop: in-order per-wave DS ops +
//   compiler lgkm/vm waits; prefetches never drained by barriers.
//   Row constants (e1,e2,cc per row) live in a 192 B LDS table (VGPR<=64 ->
//   launch_bounds(512,8) -> 4 blocks/CU = 32 waves/CU).
//   Fixed-shift softmax => j-half partials combine EXACTLY in k_comb.
// ---------------------------------------------------------------------------
#define BM 16
#define NWAVE 8

__global__ __launch_bounds__(512, 8) void k_attn(
    const float* __restrict__ A,
    const float* __restrict__ s_src,
    const float* __restrict__ s_dst,
    const short* __restrict__ WhT,
    const float* __restrict__ bmax,
    float* __restrict__ o_part,
    float* __restrict__ l_part) {
  __shared__ char smem[33536];  // [0,32768) wave tiles | epilogue reuse | scon @33280

  const int tid = threadIdx.x;
  const int wv = tid >> 6, lane = tid & 63;
  const int hi = lane >> 5, l5 = lane & 31;
  const int rsub = lane & 15, kg = lane >> 4;
  const int ib = blockIdx.x >> 1, jh = blockIdx.x & 1;
  const int i0 = ib * BM;
  const int wvbase = wv << 12;  // 4 KB per wave tile

  float* scon = (float*)(smem + 33280);  // e1[16] | e2[16] | cc[16]

  // global max of s_dst from 256 per-block maxima
  float bm = fmaxf(fmaxf(bmax[lane], bmax[lane + 64]),
                   fmaxf(bmax[lane + 128], bmax[lane + 192]));
#pragma unroll
  for (int off = 32; off > 0; off >>= 1) bm = fmaxf(bm, __shfl_xor(bm, off));
  const float tmax = bm;

  if (tid < BM) {
    float sc = s_src[i0 + tid];
    float x0 = sc + tmax;
    float m = fmaxf(fmaxf(x0, GAT_ALPHA * x0), GAT_FILL);
    scon[tid] = sc - m;
    scon[16 + tid] = GAT_ALPHA * sc - m;
    scon[32 + tid] = __expf(GAT_FILL - m);
  }
  __syncthreads();  // scon ready (only barrier before epilogue)

  bf16x8 ones;
#pragma unroll
  for (int e = 0; e < 8; ++e) ones[e] = (short)0x3F80;

  f32x4 acc0 = {0.f, 0.f, 0.f, 0.f};
  f32x4 acc1 = {0.f, 0.f, 0.f, 0.f};
  f32x4 acc2 = {0.f, 0.f, 0.f, 0.f};
  f32x4 acc3 = {0.f, 0.f, 0.f, 0.f};
  f32x4 accl = {0.f, 0.f, 0.f, 0.f};

  const short* pb0 = WhT + (size_t)(0 * 16 + rsub) * GAT_N;
  const short* pb1 = WhT + (size_t)(1 * 16 + rsub) * GAT_N;
  const short* pb2 = WhT + (size_t)(2 * 16 + rsub) * GAT_N;
  const short* pb3 = WhT + (size_t)(3 * 16 + rsub) * GAT_N;

  // A addressing: step g (0..31): chunk c=g>>3 (col += c*1024), step s=g&7
  // (row = 2s+hi); this wave's slice base = jh*4096 + wv*128 + l5*4.
  const float* Abase = A + (size_t)(i0 + hi) * GAT_N + jh * 4096 + wv * 128 + l5 * 4;
  auto aaddr = [&](int g) {
    return Abase + (size_t)((g & 7) * 2) * GAT_N + (size_t)(g >> 3) * 1024;
  };

  f32x4 buf[2];
  buf[0] = *(const f32x4*)aaddr(0);
  buf[1] = *(const f32x4*)aaddr(1);

  for (int c = 0; c < 4; ++c) {
    const int jb = jh * 4096 + c * 1024 + wv * 128;  // this wave's 128-col slice
    const f32x4 t = *(const f32x4*)(s_dst + jb + l5 * 4);

    // ---- stage: 8 steps, wave-private tile, no barrier ----
#pragma unroll
    for (int s = 0; s < 8; ++s) {
      const int g = c * 8 + s;
      f32x4 av = buf[g & 1];
      if (g + 2 < 32) buf[g & 1] = *(const f32x4*)aaddr(g + 2);
      const int row = 2 * s + hi;
      const float e1 = scon[row], e2 = scon[16 + row], cc = scon[32 + row];
      float p[4];
#pragma unroll
      for (int e = 0; e < 4; ++e) {
        float arg = fmaxf(t[e] + e1, fmaf(GAT_ALPHA, t[e], e2));
        float pe = __expf(arg);
        p[e] = (av[e] > 0.f) ? pe : cc;
      }
      __hip_bfloat162 pa = __float22bfloat162_rn(float2{p[0], p[1]});
      __hip_bfloat162 pb = __float22bfloat162_rn(float2{p[2], p[3]});
      uint2 w;
      __builtin_memcpy(&w.x, &pa, 4);
      __builtin_memcpy(&w.y, &pb, 4);
      *(uint2*)(&smem[wvbase + (row << 8) + ((l5 << 3) ^ ((row & 7) << 4))]) = w;
    }

    // ---- MFMA: 4 k-quads from own tile (in-order DS => no barrier) ----
#pragma unroll
    for (int kq = 0; kq < 4; ++kq) {
      const int raddr = wvbase + (rsub << 8) + (((kq << 6) | (kg << 4)) ^ ((rsub & 7) << 4));
      bf16x8 af = *(const bf16x8*)(&smem[raddr]);
      const int bcol = jb + (kq << 5) + (kg << 3);
      bf16x8 b0 = *(const bf16x8*)(pb0 + bcol);
      bf16x8 b1 = *(const bf16x8*)(pb1 + bcol);
      bf16x8 b2 = *(const bf16x8*)(pb2 + bcol);
      bf16x8 b3 = *(const bf16x8*)(pb3 + bcol);
      acc0 = __builtin_amdgcn_mfma_f32_16x16x32_bf16(af, b0, acc0, 0, 0, 0);
      acc1 = __builtin_amdgcn_mfma_f32_16x16x32_bf16(af, b1, acc1, 0, 0, 0);
      acc2 = __builtin_amdgcn_mfma_f32_16x16x32_bf16(af, b2, acc2, 0, 0, 0);
      acc3 = __builtin_amdgcn_mfma_f32_16x16x32_bf16(af, b3, acc3, 0, 0, 0);
      accl = __builtin_amdgcn_mfma_f32_16x16x32_bf16(af, ones, accl, 0, 0, 0);
    }
  }

  __syncthreads();  // all waves done with tiles; reuse smem for epilogue

  float* lds_o = (float*)smem;            // [8][16][64] f32 = 32 KB
  float* lds_l = (float*)(smem + 32768);  // [8][16] (within 33280 - ok: 512 B)
#pragma unroll
  for (int r = 0; r < 4; ++r) {
    const int orow = kg * 4 + r;  // C/D layout: col = lane&15, row = kg*4+reg
    lds_o[wv * 1024 + orow * 64 + 0 * 16 + rsub] = acc0[r];
    lds_o[wv * 1024 + orow * 64 + 1 * 16 + rsub] = acc1[r];
    lds_o[wv * 1024 + orow * 64 + 2 * 16 + rsub] = acc2[r];
    lds_o[wv * 1024 + orow * 64 + 3 * 16 + rsub] = acc3[r];
    if (rsub == 0) lds_l[wv * 16 + orow] = accl[r];
  }
  __syncthreads();

  for (int idx = tid; idx < BM * GAT_D; idx += 512) {
    const int r = idx >> 6, cc = idx & 63;
    float o = 0.f, ll = 0.f;
#pragma unroll
    for (int w = 0; w < NWAVE; ++w) {
      o += lds_o[w * 1024 + r * 64 + cc];
      ll += lds_l[w * 16 + r];
    }
    o_part[((size_t)jh * GAT_N + i0 + r) * GAT_D + cc] = o;
    if (cc == 0) l_part[jh * GAT_N + i0 + r] = ll;
  }
}

// ---------------------------------------------------------------------------
// Kernel 3: exact combine of the two j-half partials + ELU.
// ---------------------------------------------------------------------------
__global__ __launch_bounds__(256) void k_comb(const float* __restrict__ o_part,
                                              const float* __restrict__ l_part,
                                              float* __restrict__ out) {
  const int idx = blockIdx.x * 256 + threadIdx.x;  // f32x4 units, 131072 total
  const int row = idx >> 4;
  f32x4 o0 = *(const f32x4*)(o_part + (size_t)idx * 4);
  f32x4 o1 = *(const f32x4*)(o_part + (size_t)GAT_N * GAT_D + (size_t)idx * 4);
  const float l = l_part[row] + l_part[GAT_N + row];
  f32x4 v;
#pragma unroll
  for (int e = 0; e < 4; ++e) {
    float val = (o0[e] + o1[e]) / l;
    v[e] = (val > 0.f) ? val : (__expf(val) - 1.f);
  }
  *(f32x4*)(out + (size_t)idx * 4) = v;
}

// ---------------------------------------------------------------------------
extern "C" void kernel_launch(void* const* d_in, const int* in_sizes, int n_in,
                              void* d_out, int out_size, void* d_ws, size_t ws_size,
                              hipStream_t stream) {
  const float* h = (const float*)d_in[0];
  const float* A = (const float*)d_in[1];
  const float* W = (const float*)d_in[2];
  const float* a = (const float*)d_in[3];
  float* out = (float*)d_out;

  // ws: [0,1K) bmax | [4K,+32K) s_src | [36864,+32K) s_dst | [69632,+1M) WhT
  //     [1179648,+4M) o_part[2][8192][64] | [5373952,+64K) l_part[2][8192]
  const size_t need = 5373952 + 65536;
  if (ws_size < need) return;
  float* bmax = (float*)d_ws;
  float* s_src = (float*)((char*)d_ws + 4096);
  float* s_dst = (float*)((char*)d_ws + 36864);
  short* WhT = (short*)((char*)d_ws + 69632);
  float* o_part = (float*)((char*)d_ws + 1179648);
  float* l_part = (float*)((char*)d_ws + 5373952);

  k_prep<<<dim3(256), dim3(256), 0, stream>>>(h, W, a, s_src, s_dst, WhT, bmax);
  k_attn<<<dim3(2 * GAT_N / BM), dim3(512), 0, stream>>>(A, s_src, s_dst, WhT,
                                                         bmax, o_part, l_part);
  k_comb<<<dim3(GAT_N * GAT_D / 1024), dim3(256), 0, stream>>>(o_part, l_part, out);
}

// Round 12
// 125.726 us; speedup vs baseline: 2.9402x; 1.2645x over previous
//
#include <hip/hip_runtime.h>
#include <hip/hip_bf16.h>

#define GAT_N 8192
#define GAT_K 256
#define GAT_D 64
#define GAT_ALPHA 0.2f
#define GAT_FILL 1e-15f

typedef float f32x4 __attribute__((ext_vector_type(4)));
typedef short bf16x8 __attribute__((ext_vector_type(8)));

static __device__ __forceinline__ unsigned f2bf_u(float x) {
  unsigned u = __float_as_uint(x);
  u += 0x7FFFu + ((u >> 16) & 1u);
  return u >> 16;
}

// ---------------------------------------------------------------------------
// Kernel 1: register-tiled Wh = h @ W (validated round 4, unchanged).
// ---------------------------------------------------------------------------
__global__ __launch_bounds__(256) void k_prep(const float* __restrict__ h,
                                              const float* __restrict__ W,
                                              const float* __restrict__ av,
                                              float* __restrict__ s_src,
                                              float* __restrict__ s_dst,
                                              short* __restrict__ WhT,
                                              float* __restrict__ bmax) {
  __shared__ short T[4][64][8];
  __shared__ float wmLds[4];
  const int tid = threadIdx.x;
  const int wv = tid >> 6, lane = tid & 63;
  const int r0 = blockIdx.x * 32 + wv * 8;

  float acc[8], acc2[8];
#pragma unroll
  for (int r = 0; r < 8; ++r) { acc[r] = 0.f; acc2[r] = 0.f; }

  for (int kc = 0; kc < GAT_K; kc += 32) {
    float Wreg[32];
#pragma unroll
    for (int e = 0; e < 32; ++e) Wreg[e] = W[(size_t)(kc + e) * GAT_D + lane];
#pragma unroll
    for (int r = 0; r < 8; ++r) {
      const f32x4* h4 = (const f32x4*)(h + (size_t)(r0 + r) * GAT_K + kc);
#pragma unroll
      for (int q = 0; q < 8; ++q) {
        f32x4 hv = h4[q];
        acc[r] += hv[0] * Wreg[4 * q + 0];
        acc2[r] += hv[1] * Wreg[4 * q + 1];
        acc[r] += hv[2] * Wreg[4 * q + 2];
        acc2[r] += hv[3] * Wreg[4 * q + 3];
      }
    }
  }

  const float a_s = av[lane];
  const float a_d = av[64 + lane];
  float wmax = -3.0e38f;
#pragma unroll
  for (int r = 0; r < 8; ++r) {
    const float accf = acc[r] + acc2[r];
    T[wv][lane][r] = (short)f2bf_u(accf);
    float vs = accf * a_s, vd = accf * a_d;
#pragma unroll
    for (int off = 32; off > 0; off >>= 1) {
      vs += __shfl_xor(vs, off);
      vd += __shfl_xor(vd, off);
    }
    if (lane == 0) { s_src[r0 + r] = vs; s_dst[r0 + r] = vd; }
    wmax = fmaxf(wmax, vd);
  }
  bf16x8 vt = *(const bf16x8*)&T[wv][lane][0];
  *(bf16x8*)(WhT + (size_t)lane * GAT_N + r0) = vt;

  if (lane == 0) wmLds[wv] = wmax;
  __syncthreads();
  if (tid == 0) {
    bmax[blockIdx.x] = fmaxf(fmaxf(wmLds[0], wmLds[1]), fmaxf(wmLds[2], wmLds[3]));
  }
}

// ---------------------------------------------------------------------------
// Kernel 2: register-deep, barrier-free fused masked-softmax + P@Wh.
//   512 blocks x 256 thr (4 waves). Each wave: private 4 KB P tile
//   ([16][128] bf16, XOR-swizzled), 16 chunks of 128 cols.
//   FULL-CHUNK register prefetch, one chunk AHEAD of use (static-index
//   rotating arrays): 8 A-loads (32 VGPR) + 16 B-fragments (64 VGPR) + t.
//   launch_bounds(256,2) -> VGPR cap 256 (expect ~190): ILP replaces
//   occupancy; per-wave stalls ~0, kernel streams A at HBM rate.
//   No __syncthreads in the loop (wave-private tile, in-order DS).
//   Fixed-shift factorized softmax (R9 math, validated):
//     P = edge ? (t>=-s ? E1_j*F1_r : E2_j*F2_r) : cc_r
// ---------------------------------------------------------------------------
#define BM 16

__global__ __launch_bounds__(256, 2) void k_attn(
    const float* __restrict__ A,
    const float* __restrict__ s_src,
    const float* __restrict__ s_dst,
    const short* __restrict__ WhT,
    const float* __restrict__ bmax,
    float* __restrict__ out) {
  __shared__ char smem[16640];  // 4 x 4KB wave tiles; epilogue reuse + lds_l

  const int tid = threadIdx.x;
  const int wv = tid >> 6, lane = tid & 63;
  const int hi = lane >> 5, l5 = lane & 31;
  const int rsub = lane & 15, kg = lane >> 4;
  const int i0 = blockIdx.x * BM;
  const int wvbase = wv << 12;

  // global max of s_dst from 256 per-block maxima
  float bm = fmaxf(fmaxf(bmax[lane], bmax[lane + 64]),
                   fmaxf(bmax[lane + 128], bmax[lane + 192]));
#pragma unroll
  for (int off = 32; off > 0; off >>= 1) bm = fmaxf(bm, __shfl_xor(bm, off));
  const float tmax = bm;

  // per-thread row constants (row = 2s + hi differs across half-wave -> VGPR)
  float F1_[8], F2_[8], ns_[8], cc_[8];
#pragma unroll
  for (int s = 0; s < 8; ++s) {
    const int row = 2 * s + hi;
    float sc = s_src[i0 + row];
    float x0 = sc + tmax;
    float m = fmaxf(fmaxf(x0, GAT_ALPHA * x0), GAT_FILL);
    F1_[s] = __expf(sc - m);
    F2_[s] = __expf(GAT_ALPHA * sc - m);
    ns_[s] = -sc;
    cc_[s] = __expf(GAT_FILL - m);
  }

  bf16x8 ones;
#pragma unroll
  for (int e = 0; e < 8; ++e) ones[e] = (short)0x3F80;

  f32x4 acc0 = {0.f, 0.f, 0.f, 0.f};
  f32x4 acc1 = {0.f, 0.f, 0.f, 0.f};
  f32x4 acc2 = {0.f, 0.f, 0.f, 0.f};
  f32x4 acc3 = {0.f, 0.f, 0.f, 0.f};
  f32x4 accl = {0.f, 0.f, 0.f, 0.f};

  const int colbase = wv * 128;  // this wave's 128-col slice within each chunk
  const float* Abase = A + (size_t)(i0 + hi) * GAT_N + colbase + l5 * 4;
  const short* pb0 = WhT + (size_t)(0 * 16 + rsub) * GAT_N + colbase + (kg << 3);
  const short* pb1 = WhT + (size_t)(1 * 16 + rsub) * GAT_N + colbase + (kg << 3);
  const short* pb2 = WhT + (size_t)(2 * 16 + rsub) * GAT_N + colbase + (kg << 3);
  const short* pb3 = WhT + (size_t)(3 * 16 + rsub) * GAT_N + colbase + (kg << 3);
  const float* tbase = s_dst + colbase + l5 * 4;

  // ---- prologue: full prefetch of chunk 0 into registers ----
  f32x4 Ar[8];
#pragma unroll
  for (int s = 0; s < 8; ++s)
    Ar[s] = *(const f32x4*)(Abase + (size_t)(2 * s) * GAT_N);
  bf16x8 bq0[4], bq1[4], bq2[4], bq3[4];
#pragma unroll
  for (int kq = 0; kq < 4; ++kq) {
    bq0[kq] = *(const bf16x8*)(pb0 + (kq << 5));
    bq1[kq] = *(const bf16x8*)(pb1 + (kq << 5));
    bq2[kq] = *(const bf16x8*)(pb2 + (kq << 5));
    bq3[kq] = *(const bf16x8*)(pb3 + (kq << 5));
  }
  f32x4 tcur = *(const f32x4*)tbase;

  for (int c = 0; c < 16; ++c) {
    const int jc = c * 512;
    const int jn = (c < 15) ? jc + 512 : jc;  // clamp: last iter re-reads (L2-hit)

    f32x4 tnxt = *(const f32x4*)(tbase + jn);

    // per-chunk exps, shared across all 16 rows
    f32x4 E1, E2;
#pragma unroll
    for (int e = 0; e < 4; ++e) {
      E1[e] = __expf(tcur[e]);
      E2[e] = __expf(GAT_ALPHA * tcur[e]);
    }

    // ---- stage: 8 steps; consume Ar[s], immediately re-issue for chunk c+1 ----
#pragma unroll
    for (int s = 0; s < 8; ++s) {
      f32x4 av = Ar[s];
      Ar[s] = *(const f32x4*)(Abase + (size_t)(2 * s) * GAT_N + jn);
      float p[4];
#pragma unroll
      for (int e = 0; e < 4; ++e) {
        float m1 = E1[e] * F1_[s];
        float m2 = E2[e] * F2_[s];
        float psel = (tcur[e] >= ns_[s]) ? m1 : m2;
        p[e] = (av[e] > 0.f) ? psel : cc_[s];
      }
      __hip_bfloat162 pa = __float22bfloat162_rn(float2{p[0], p[1]});
      __hip_bfloat162 pb = __float22bfloat162_rn(float2{p[2], p[3]});
      uint2 w;
      __builtin_memcpy(&w.x, &pa, 4);
      __builtin_memcpy(&w.y, &pb, 4);
      const int row = 2 * s + hi;
      *(uint2*)(&smem[wvbase + (row << 8) + ((l5 << 3) ^ ((row & 7) << 4))]) = w;
    }

    // ---- MFMA: 4 k-quads; consume bq*[kq], immediately re-issue for c+1 ----
#pragma unroll
    for (int kq = 0; kq < 4; ++kq) {
      const int raddr =
          wvbase + (rsub << 8) + (((kq << 6) | (kg << 4)) ^ ((rsub & 7) << 4));
      bf16x8 af = *(const bf16x8*)(&smem[raddr]);
      acc0 = __builtin_amdgcn_mfma_f32_16x16x32_bf16(af, bq0[kq], acc0, 0, 0, 0);
      acc1 = __builtin_amdgcn_mfma_f32_16x16x32_bf16(af, bq1[kq], acc1, 0, 0, 0);
      acc2 = __builtin_amdgcn_mfma_f32_16x16x32_bf16(af, bq2[kq], acc2, 0, 0, 0);
      acc3 = __builtin_amdgcn_mfma_f32_16x16x32_bf16(af, bq3[kq], acc3, 0, 0, 0);
      accl = __builtin_amdgcn_mfma_f32_16x16x32_bf16(af, ones, accl, 0, 0, 0);
      bq0[kq] = *(const bf16x8*)(pb0 + jn + (kq << 5));
      bq1[kq] = *(const bf16x8*)(pb1 + jn + (kq << 5));
      bq2[kq] = *(const bf16x8*)(pb2 + jn + (kq << 5));
      bq3[kq] = *(const bf16x8*)(pb3 + jn + (kq << 5));
    }
    tcur = tnxt;
  }

  __syncthreads();  // all waves done with tiles; reuse smem for epilogue

  // ---- epilogue: exact 4-wave combine + ELU ----
  float* lds_o = (float*)smem;            // [4][16][64] f32 = 16 KB (own region)
  float* lds_l = (float*)(smem + 16384);  // [4][16]
#pragma unroll
  for (int r = 0; r < 4; ++r) {
    const int orow = kg * 4 + r;  // C/D layout: col = lane&15, row = kg*4+reg
    lds_o[wv * 1024 + orow * 64 + 0 * 16 + rsub] = acc0[r];
    lds_o[wv * 1024 + orow * 64 + 1 * 16 + rsub] = acc1[r];
    lds_o[wv * 1024 + orow * 64 + 2 * 16 + rsub] = acc2[r];
    lds_o[wv * 1024 + orow * 64 + 3 * 16 + rsub] = acc3[r];
    if (rsub == 0) lds_l[wv * 16 + orow] = accl[r];
  }
  __syncthreads();

  for (int idx = tid; idx < BM * GAT_D; idx += 256) {
    const int r = idx >> 6, col = idx & 63;
    float o = 0.f, ll = 0.f;
#pragma unroll
    for (int w = 0; w < 4; ++w) {
      o += lds_o[w * 1024 + r * 64 + col];
      ll += lds_l[w * 16 + r];
    }
    float val = o / ll;
    out[(size_t)(i0 + r) * GAT_D + col] = (val > 0.f) ? val : (__expf(val) - 1.f);
  }
}

// ---------------------------------------------------------------------------
extern "C" void kernel_launch(void* const* d_in, const int* in_sizes, int n_in,
                              void* d_out, int out_size, void* d_ws, size_t ws_size,
                              hipStream_t stream) {
  const float* h = (const float*)d_in[0];
  const float* A = (const float*)d_in[1];
  const float* W = (const float*)d_in[2];
  const float* a = (const float*)d_in[3];
  float* out = (float*)d_out;

  // ws layout: [0,1K) bmax | [4K,+32K) s_src | [36864,+32K) s_dst | [69632,+1M) WhT
  const size_t need = 69632 + (size_t)GAT_D * GAT_N * 2;
  if (ws_size < need) return;
  float* bmax = (float*)d_ws;
  float* s_src = (float*)((char*)d_ws + 4096);
  float* s_dst = (float*)((char*)d_ws + 36864);
  short* WhT = (short*)((char*)d_ws + 69632);

  k_prep<<<dim3(256), dim3(256), 0, stream>>>(h, W, a, s_src, s_dst, WhT, bmax);
  k_attn<<<dim3(GAT_N / BM), dim3(256), 0, stream>>>(A, s_src, s_dst, WhT, bmax, out);
}